// Round 2
// baseline (491.897 us; speedup 1.0000x reference)
//
#include <hip/hip_runtime.h>

// Problem constants
#define DD   512
#define KK_N 32
#define HH   4
#define DH   128
#define BN_TOT 4096

// ---------------------------------------------------------------------------
// Generic batched SGEMM, C[r][o] = sum_k A[r*lda+k] * Bop[o][k] (+ bias[o])
//   BT=true : B stored [N][K] row-major (B[o*ldb+k])   — "NT"
//   BT=false: B stored [K][N] row-major (B[k*ldb+o])   — "NN"
// Tile 64x64, 256 threads, K-chunk 16. All dims assumed multiples of tile.
// ---------------------------------------------------------------------------
template<bool BT>
__global__ __launch_bounds__(256)
void sgemm_nt(const float* __restrict__ A, int lda, int batchA,
              const float* __restrict__ B, int ldb, int batchB,
              float* __restrict__ C, int ldc, int batchC,
              const float* __restrict__ bias, int batchBias,
              int Kd)
{
    const int bz = blockIdx.z;
    A += (long)bz * batchA;
    B += (long)bz * batchB;
    C += (long)bz * batchC;
    if (bias) bias += (long)bz * batchBias;

    __shared__ __align__(16) float As[16][68];
    __shared__ __align__(16) float Bs[16][68];

    const int t  = threadIdx.x;
    const int tx = t & 15;          // output col group (tx*4)
    const int ty = t >> 4;          // output row group (ty*4)
    const int rbase = blockIdx.y * 64;
    const int obase = blockIdx.x * 64;

    const int arow = t >> 2;        // 0..63  (staging row for NT-style loads)
    const int ak4  = t & 3;         // 0..3   (staging k-group)
    const int bkr  = t >> 4;        // 0..15  (staging k-row for NN loads)
    const int boc  = t & 15;        // 0..15  (staging col group for NN loads)

    float acc[4][4] = {};

    for (int k0 = 0; k0 < Kd; k0 += 16) {
        // global loads for this tile
        float4 av = *(const float4*)&A[(long)(rbase + arow) * lda + k0 + ak4 * 4];
        float4 bv;
        if (BT) {
            bv = *(const float4*)&B[(long)(obase + arow) * ldb + k0 + ak4 * 4];
        } else {
            bv = *(const float4*)&B[(long)(k0 + bkr) * ldb + obase + boc * 4];
        }
        __syncthreads();   // previous iteration's LDS reads must be done
        // A: transpose-store to As[kk][row]
        As[ak4*4+0][arow] = av.x; As[ak4*4+1][arow] = av.y;
        As[ak4*4+2][arow] = av.z; As[ak4*4+3][arow] = av.w;
        if (BT) {
            Bs[ak4*4+0][arow] = bv.x; Bs[ak4*4+1][arow] = bv.y;
            Bs[ak4*4+2][arow] = bv.z; Bs[ak4*4+3][arow] = bv.w;
        } else {
            *(float4*)&Bs[bkr][boc*4] = bv;
        }
        __syncthreads();
#pragma unroll
        for (int kk = 0; kk < 16; kk++) {
            float4 a = *(const float4*)&As[kk][ty*4];
            float4 b = *(const float4*)&Bs[kk][tx*4];
            float af[4] = {a.x, a.y, a.z, a.w};
            float bf[4] = {b.x, b.y, b.z, b.w};
#pragma unroll
            for (int i = 0; i < 4; i++)
#pragma unroll
                for (int j = 0; j < 4; j++)
                    acc[i][j] = fmaf(af[i], bf[j], acc[i][j]);
        }
    }

    float4 bias4 = make_float4(0.f, 0.f, 0.f, 0.f);
    if (bias) bias4 = *(const float4*)&bias[obase + tx*4];
#pragma unroll
    for (int i = 0; i < 4; i++) {
        float4 o;
        o.x = acc[i][0] + bias4.x;
        o.y = acc[i][1] + bias4.y;
        o.z = acc[i][2] + bias4.z;
        o.w = acc[i][3] + bias4.w;
        *(float4*)&C[(long)(rbase + ty*4 + i) * ldc + obase + tx*4] = o;
    }
}

// ---------------------------------------------------------------------------
// Fused scores -> masked online softmax -> attention-weighted embedding sum.
// One block per (b,n). wne may alias g (read fully before written, same block).
// ---------------------------------------------------------------------------
__global__ __launch_bounds__(256)
void attn_fused(const float* __restrict__ ne,    // [BN][32][512]
                const int*   __restrict__ mask,  // [BN][32]
                const float* __restrict__ q,     // [BN][512]
                const float* g,                  // [BN][4][512]  (no restrict: aliases wne)
                const float* __restrict__ bk,    // [512]
                float* wne)                      // [BN][4][512]
{
    const int bn   = blockIdx.x;
    const int t    = threadIdx.x;
    const int wave = t >> 6;
    const int lane = t & 63;

    __shared__ __align__(16) float ne_s[16][516];   // chunk of 16 neighbors, padded
    __shared__ __align__(16) float g_s[HH * DD];
    __shared__ float part[4][16][HH];               // [wave][k][h]
    __shared__ float p_s[HH][16];
    __shared__ float c_s[HH];
    __shared__ float m_s[HH], l_s[HH], alpha_s[HH];

    // stage g (query-side projected vectors), 2048 floats
    {
        const float4* gs = (const float4*)(g + (long)bn * (HH * DD));
        float4 v0 = gs[t];
        float4 v1 = gs[t + 256];
        *(float4*)&g_s[t * 4]         = v0;
        *(float4*)&g_s[(t + 256) * 4] = v1;
    }
    // c[h] = q_h . bk_h   (wave w handles head w; 64 lanes x 2 elems = 128)
    {
        float2 q2 = *(const float2*)&q[(long)bn * DD + wave * DH + lane * 2];
        float2 b2 = *(const float2*)&bk[wave * DH + lane * 2];
        float cp = q2.x * b2.x + q2.y * b2.y;
#pragma unroll
        for (int off = 32; off >= 1; off >>= 1)
            cp += __shfl_xor(cp, off, 64);
        if (lane == 0) c_s[wave] = cp;
    }
    if (t < HH) { m_s[t] = -__builtin_inff(); l_s[t] = 0.f; }

    float wacc[8] = {};
    const int h_own = t >> 6;            // head owned in weighted-sum phase
    const int d8    = (t & 63) * 8;      // 8-float slice of D
    const int kk    = t & 15;            // neighbor within chunk (scores phase)
    const int rep   = t >> 4;            // D-slice 32 floats (scores phase)

    for (int ch = 0; ch < 2; ch++) {
        __syncthreads();
        // load chunk of 16 neighbor rows (contiguous 32 KB) into LDS
        {
            const float4* src = (const float4*)(ne + (long)bn * (KK_N * DD) + ch * (16 * DD));
#pragma unroll
            for (int i = 0; i < 8; i++) {
                int f = i * 256 + t;
                float4 v = src[f];
                *(float4*)&ne_s[f >> 7][(f & 127) * 4] = v;
            }
        }
        __syncthreads();
        // scores: 16 k x 4 h dot products of length 512, split 16 ways over D
        {
            float acc[HH] = {};
#pragma unroll
            for (int i = 0; i < 8; i++) {
                float4 nv = *(const float4*)&ne_s[kk][rep * 32 + i * 4];
#pragma unroll
                for (int h = 0; h < HH; h++) {
                    float4 gv = *(const float4*)&g_s[h * DD + rep * 32 + i * 4];
                    acc[h] = fmaf(nv.x, gv.x, acc[h]);
                    acc[h] = fmaf(nv.y, gv.y, acc[h]);
                    acc[h] = fmaf(nv.z, gv.z, acc[h]);
                    acc[h] = fmaf(nv.w, gv.w, acc[h]);
                }
            }
#pragma unroll
            for (int h = 0; h < HH; h++) {
                acc[h] += __shfl_xor(acc[h], 16, 64);
                acc[h] += __shfl_xor(acc[h], 32, 64);
            }
            if ((t & 48) == 0) {
#pragma unroll
                for (int h = 0; h < HH; h++) part[wave][kk][h] = acc[h];
            }
        }
        __syncthreads();
        // online softmax update (wave 0 only; lanes: k_i = bits 0..3, h = bits 4..5)
        if (t < 64) {
            int k_i = t & 15, h = t >> 4;
            float s = part[0][k_i][h] + part[1][k_i][h] + part[2][k_i][h]
                    + part[3][k_i][h] + c_s[h];
            if (mask[(long)bn * KK_N + ch * 16 + k_i] == 0) s = -1.0e9f;
            float mx = s;
#pragma unroll
            for (int off = 8; off >= 1; off >>= 1)
                mx = fmaxf(mx, __shfl_xor(mx, off, 64));
            float m_old = m_s[h];
            float m_new = fmaxf(m_old, mx);
            float p = expf(s - m_new);
            float sm = p;
#pragma unroll
            for (int off = 8; off >= 1; off >>= 1)
                sm += __shfl_xor(sm, off, 64);
            p_s[h][k_i] = p;
            if (k_i == 0) {
                float alpha = expf(m_old - m_new);
                alpha_s[h] = alpha;
                l_s[h] = l_s[h] * alpha + sm;
                m_s[h] = m_new;
            }
        }
        __syncthreads();
        // weighted accumulate: thread owns (h_own, 8 floats of D)
        {
            float alpha = alpha_s[h_own];
#pragma unroll
            for (int j = 0; j < 8; j++) wacc[j] *= alpha;
#pragma unroll
            for (int k2 = 0; k2 < 16; k2++) {
                float pk = p_s[h_own][k2];
                float4 n0 = *(const float4*)&ne_s[k2][d8];
                float4 n1 = *(const float4*)&ne_s[k2][d8 + 4];
                wacc[0] = fmaf(pk, n0.x, wacc[0]);
                wacc[1] = fmaf(pk, n0.y, wacc[1]);
                wacc[2] = fmaf(pk, n0.z, wacc[2]);
                wacc[3] = fmaf(pk, n0.w, wacc[3]);
                wacc[4] = fmaf(pk, n1.x, wacc[4]);
                wacc[5] = fmaf(pk, n1.y, wacc[5]);
                wacc[6] = fmaf(pk, n1.z, wacc[6]);
                wacc[7] = fmaf(pk, n1.w, wacc[7]);
            }
        }
    }
    // finalize: normalize and write wne[bn] (flat offset == t*8 by construction)
    float rl = 1.0f / l_s[h_own];
    float4 o0 = make_float4(wacc[0] * rl, wacc[1] * rl, wacc[2] * rl, wacc[3] * rl);
    float4 o1 = make_float4(wacc[4] * rl, wacc[5] * rl, wacc[6] * rl, wacc[7] * rl);
    float* dst = wne + (long)bn * (HH * DD) + t * 8;
    *(float4*)&dst[0] = o0;
    *(float4*)&dst[4] = o1;
}

// ---------------------------------------------------------------------------
extern "C" void kernel_launch(void* const* d_in, const int* in_sizes, int n_in,
                              void* d_out, int out_size, void* d_ws, size_t ws_size,
                              hipStream_t stream) {
    (void)in_sizes; (void)n_in; (void)out_size; (void)ws_size;
    const float* ne  = (const float*)d_in[0];
    const int*   msk = (const int*)  d_in[1];
    const float* x   = (const float*)d_in[2];
    const float* Wq  = (const float*)d_in[3];
    const float* bq  = (const float*)d_in[4];
    const float* Wk  = (const float*)d_in[5];
    const float* bk  = (const float*)d_in[6];
    const float* Wv  = (const float*)d_in[7];
    const float* bv  = (const float*)d_in[8];
    float* out = (float*)d_out;

    // workspace: q [4096*512] then g/wne [4096*4*512] (aliased) => ~42 MB
    float* q_ws = (float*)d_ws;
    float* g_ws = q_ws + (long)BN_TOT * DD;

    dim3 blk(256);
    // 1) q = x @ Wq^T + bq              (NT: Wq is [out][in])
    sgemm_nt<true ><<<dim3(8, 64, 1), blk, 0, stream>>>(
        x, DD, 0, Wq, DD, 0, q_ws, DD, 0, bq, 0, DD);
    // 2) g[:,h,:] = q_h @ Wk_h          (NN: B[o][k] = Wk[h*128+k][o])
    sgemm_nt<false><<<dim3(8, 64, HH), blk, 0, stream>>>(
        q_ws, DD, DH, Wk, DD, DH * DD, g_ws, HH * DD, DD, nullptr, 0, DH);
    // 3) fused scores/softmax/weighted-sum -> wne (aliases g_ws)
    attn_fused<<<dim3(BN_TOT), blk, 0, stream>>>(ne, msk, q_ws, g_ws, bk, g_ws);
    // 4) out[:,h*128:...] = wne_h @ Wv_h^T + bv_h   (NT)
    sgemm_nt<true ><<<dim3(2, 64, HH), blk, 0, stream>>>(
        g_ws, HH * DD, DD, Wv, DD, DH * DD, out, DD, DH, bv, DH, DD);
}